// Round 15
// baseline (149.764 us; speedup 1.0000x reference)
//
#include <hip/hip_runtime.h>

typedef __attribute__((ext_vector_type(8))) short bf16x8;
typedef __attribute__((ext_vector_type(4))) float f32x4;
typedef unsigned short u16;

__device__ __forceinline__ float bf2f(u16 u) {
    return __builtin_bit_cast(float, ((unsigned int)u) << 16);
}
__device__ __forceinline__ u16 f2bf(float f) {
    unsigned int x = __builtin_bit_cast(unsigned int, f);
    x += 0x7FFFu + ((x >> 16) & 1u);   // RNE
    return (u16)(x >> 16);
}

typedef const __attribute__((address_space(1))) void* gas_t;
typedef __attribute__((address_space(3))) void* las_t;
__device__ __forceinline__ void load_lds16(const u16* g, u16* l) {
    __builtin_amdgcn_global_load_lds((gas_t)g, (las_t)l, 16, 0, 0);
}

// ---------------- prep: weight cvt (blocks 0..767) + LayerNorm1 (blocks 768..2815) ----------------
__global__ __launch_bounds__(256) void prep_kernel(
    const float* __restrict__ s0, const float* __restrict__ s1,
    const float* __restrict__ s2, const float* __restrict__ s3,
    u16* __restrict__ dst,
    const float* __restrict__ x, const float* __restrict__ g,
    const float* __restrict__ b, u16* __restrict__ y)
{
    if (blockIdx.x < 768) {
        const int i4 = (blockIdx.x * 256 + threadIdx.x) * 4;
        const float* src;
        int off;
        if      (i4 < 196608) { src = s0; off = i4; }
        else if (i4 < 262144) { src = s1; off = i4 - 196608; }
        else if (i4 < 524288) { src = s2; off = i4 - 262144; }
        else                  { src = s3; off = i4 - 524288; }
        float4 v = *(const float4*)(src + off);
        ushort4 o;
        o.x = f2bf(v.x); o.y = f2bf(v.y); o.z = f2bf(v.z); o.w = f2bf(v.w);
        *(ushort4*)(dst + i4) = o;
        return;
    }
    const int tok  = (blockIdx.x - 768) * 4 + (threadIdx.x >> 6);
    const int lane = threadIdx.x & 63;
    float4 v = *(const float4*)(x + (size_t)tok * 256 + lane * 4);
    float s  = v.x + v.y + v.z + v.w;
    float sq = v.x*v.x + v.y*v.y + v.z*v.z + v.w*v.w;
    #pragma unroll
    for (int off = 32; off; off >>= 1) {
        s  += __shfl_xor(s, off);
        sq += __shfl_xor(sq, off);
    }
    float mean = s * (1.0f / 256.0f);
    float var  = sq * (1.0f / 256.0f) - mean * mean;
    float rs   = rsqrtf(var + 1e-5f);
    float4 gv = *(const float4*)(g + lane * 4);
    float4 bv = *(const float4*)(b + lane * 4);
    ushort4 o;
    o.x = f2bf((v.x - mean) * rs * gv.x + bv.x);
    o.y = f2bf((v.y - mean) * rs * gv.y + bv.y);
    o.z = f2bf((v.z - mean) * rs * gv.z + bv.z);
    o.w = f2bf((v.w - mean) * rs * gv.w + bv.w);
    *(ushort4*)(y + (size_t)tok * 256 + lane * 4) = o;
}

// ---------------- BMxBN-tile GEMM, BK=64, single-buffer (R2/R9-proven): out = A@W^T + bias ----------------
// EPI: 1 qkv (cols<256 scaled, bf16 out)
template<int BM, int BN, int N, int K, int EPI>
__global__ __launch_bounds__(256) void gemm(
    const u16* __restrict__ A, const u16* __restrict__ W,
    const float* __restrict__ bias, const float* __restrict__ res,
    void* __restrict__ outv)
{
    constexpr int WMT = BM / 32;
    constexpr int WNT = BN / 32;
    constexpr int AR  = BM / 32;
    constexpr int BR  = BN / 32;

    __shared__ u16 As[BM * 64];
    __shared__ u16 Bs[BN * 64];
    const int tid  = threadIdx.x;
    const int lane = tid & 63;
    const int wave = tid >> 6;
    const int m0   = blockIdx.x * BM;
    const int n0   = blockIdx.y * BN;
    const int wm0  = (wave >> 1) * (BM / 2);
    const int wn0  = (wave & 1) * (BN / 2);

    f32x4 acc[WMT][WNT];
    #pragma unroll
    for (int mt = 0; mt < WMT; ++mt)
        #pragma unroll
        for (int nt = 0; nt < WNT; ++nt)
            acc[mt][nt] = (f32x4){0.f, 0.f, 0.f, 0.f};

    int soffA[AR];
    #pragma unroll
    for (int r = 0; r < AR; ++r) {
        const int s   = r * 256 + tid;
        const int row = s >> 3;
        const int c   = (s & 7) ^ (row & 7);
        soffA[r] = row * K + c * 8;
    }
    int soffB[BR];
    #pragma unroll
    for (int r = 0; r < BR; ++r) {
        const int s   = r * 256 + tid;
        const int row = s >> 3;
        const int c   = (s & 7) ^ (row & 7);
        soffB[r] = row * K + c * 8;
    }
    const int fr = lane & 15;
    const int fc = lane >> 4;

    for (int k0 = 0; k0 < K; k0 += 64) {
        __syncthreads();
        #pragma unroll
        for (int r = 0; r < AR; ++r)
            load_lds16(A + (size_t)m0 * K + k0 + soffA[r], As + (r * 256 + tid) * 8);
        #pragma unroll
        for (int r = 0; r < BR; ++r)
            load_lds16(W + (size_t)n0 * K + k0 + soffB[r], Bs + (r * 256 + tid) * 8);
        __syncthreads();
        #pragma unroll
        for (int ks = 0; ks < 2; ++ks) {
            bf16x8 af[WMT], bw[WNT];
            #pragma unroll
            for (int mt = 0; mt < WMT; ++mt) {
                const int rr   = wm0 + mt * 16 + fr;
                const int phys = (ks * 4 + fc) ^ (rr & 7);
                af[mt] = *(const bf16x8*)(As + rr * 64 + phys * 8);
            }
            #pragma unroll
            for (int nt = 0; nt < WNT; ++nt) {
                const int rr   = wn0 + nt * 16 + fr;
                const int phys = (ks * 4 + fc) ^ (rr & 7);
                bw[nt] = *(const bf16x8*)(Bs + rr * 64 + phys * 8);
            }
            #pragma unroll
            for (int mt = 0; mt < WMT; ++mt)
                #pragma unroll
                for (int nt = 0; nt < WNT; ++nt)
                    acc[mt][nt] = __builtin_amdgcn_mfma_f32_16x16x32_bf16(af[mt], bw[nt], acc[mt][nt], 0, 0, 0);
        }
    }

    const int col = lane & 15;
    const int rb  = (lane >> 4) * 4;
    #pragma unroll
    for (int nt = 0; nt < WNT; ++nt) {
        const int n  = n0 + wn0 + nt * 16 + col;
        const float bv = bias[n];
        #pragma unroll
        for (int mt = 0; mt < WMT; ++mt) {
            #pragma unroll
            for (int r = 0; r < 4; ++r) {
                const int m = m0 + wm0 + mt * 16 + rb + r;
                float v = acc[mt][nt][r] + bv;
                if (EPI == 1) {
                    if (n < 256) v *= 0.1767766952966369f;  // 1/sqrt(32), q only
                    ((u16*)outv)[(size_t)m * N + n] = f2bf(v);
                }
            }
        }
    }
}

// ---------- fused MFMA attention (8 waves = 8 heads) + proj + residual + LayerNorm2 ----------
// R12-exact (session best): K/Q cooperatively staged via coalesced global_load_lds,
// V as 32B-coalesced per-lane gather, P bf16 hi+lo compensated.
__global__ __launch_bounds__(512) void attn_proj_kernel(
    const u16* __restrict__ qkv, const float* __restrict__ rpb,
    const u16* __restrict__ projW, const float* __restrict__ proj_b,
    const float* __restrict__ xres, const float* __restrict__ g2,
    const float* __restrict__ b2, float* __restrict__ x1,
    u16* __restrict__ ln2)
{
    __shared__ u16   Ks[112 * 256];    // [key][256ch], 16B chunk c at phys c^(key&31)
    __shared__ u16   Qs[16 * 256];     // [tok][256ch], same swizzle
    __shared__ u16   ao[16 * 256];     // attn out, chunk c of row t at c^(t&7)
    __shared__ float rpbs[8 * 177];    // per-head table (169) + sentinel (-1e30)
    __shared__ float red[8][16][2];

    const int tid = threadIdx.x;
    const int l   = tid & 63;
    const int w   = tid >> 6;          // wave = head
    const int B   = blockIdx.x;
    const int tile = (B & 7) * 64 + (B >> 3);   // XCD swizzle over 512 blocks
    const int bb   = tile >> 8;
    const int rem  = tile & 255;
    const int ti0  = (rem >> 4) << 2;
    const int tj0  = (rem & 15) << 2;
    const int oh   = min(max(ti0 - 3, 0), 54);
    const int ow   = min(max(tj0 - 3, 0), 54);
    const int tokbase = bb * 4096;

    // ---- cooperative staging: K (7 rounds), Q (1 round), coalesced + source-swizzled ----
    #pragma unroll
    for (int r = 0; r < 7; ++r) {
        const int s   = r * 512 + tid;
        const int key = s >> 5;                  // 32 chunks per 512B row
        const int pc  = s & 31;
        const int gc  = pc ^ (key & 31);
        const int kkc = min(key, 99);
        const int tr  = (kkc * 205) >> 11, tc = kkc - tr * 10;
        const int tokg = tokbase + (oh + tr) * 64 + (ow + tc);
        load_lds16(qkv + (size_t)tokg * 768 + 256 + gc * 8, Ks + s * 8);
    }
    {
        const int s   = tid;
        const int tok = s >> 5;
        const int pc  = s & 31;
        const int gc  = pc ^ (tok & 31);
        const int tokq = tokbase + (ti0 + (tok >> 2)) * 64 + (tj0 + (tok & 3));
        load_lds16(qkv + (size_t)tokq * 768 + gc * 8, Qs + s * 8);
    }
    #pragma unroll
    for (int r = 0; r < 3; ++r) {
        const int idx = r * 512 + tid;
        if (idx < 1416) {
            const int hh = idx / 177;
            const int ii = idx - hh * 177;
            rpbs[idx] = (ii < 169) ? rpb[hh * 169 + ii] : -1e30f;
        }
    }

    const int q = l & 15;    // doubles as output channel sub-index
    const int g = l >> 4;

    // ---- per-lane bias indices + V tokens (keys 16t+4g+r) ----
    const int i  = ti0 + (q >> 2), j = tj0 + (q & 3);
    const int sh = min(max(i - 3, 0), 57), sw = min(max(j - 3, 0), 57);
    const int khb = sh - oh, kwb = sw - ow;
    const int bh0 = oh - i + 6, bw0 = ow - j + 6;
    int bidx[7][4];
    int vtok[7][4];
    #pragma unroll
    for (int t = 0; t < 7; ++t)
        #pragma unroll
        for (int r = 0; r < 4; ++r) {
            const int kk  = 16 * t + 4 * g + r;
            const int kkc = min(kk, 99);
            const int hr  = (kkc * 205) >> 11;
            const int hc  = kkc - hr * 10;
            vtok[t][r] = tokbase + (oh + hr) * 64 + (ow + hc);
            const bool valid = (kk < 100)
                && ((unsigned)(hr - khb) < 7u) && ((unsigned)(hc - kwb) < 7u);
            bidx[t][r] = valid ? (bh0 + hr) * 13 + (bw0 + hc) : 169;  // sentinel
        }

    __syncthreads();   // staging + rpbs visible to all waves

    // ---- fragment reads from LDS (2-way bank-aliased via chunk-XOR swizzle) ----
    const int cw = w * 4 + g;                    // logical 16B chunk for this head/lane
    const bf16x8 qf = *(const bf16x8*)(Qs + q * 256 + (cw ^ (q & 31)) * 8);
    bf16x8 kf[7];
    #pragma unroll
    for (int t = 0; t < 7; ++t) {
        const int key = 16 * t + q;
        kf[t] = *(const bf16x8*)(Ks + key * 256 + (cw ^ (key & 31)) * 8);
    }

    // ---- QK^T: S[t] reg r = S[key 16t+4g+r][q] ----
    f32x4 S[7];
    #pragma unroll
    for (int t = 0; t < 7; ++t)
        S[t] = __builtin_amdgcn_mfma_f32_16x16x32_bf16(kf[t], qf, (f32x4){0.f,0.f,0.f,0.f}, 0, 0, 0);

    // ---- bias + mask + softmax (in-lane + 2 shfl pairs) ----
    const float* rpbh = rpbs + w * 177;
    float p[7][4];
    float mx = -1e30f;
    #pragma unroll
    for (int t = 0; t < 7; ++t)
        #pragma unroll
        for (int r = 0; r < 4; ++r) {
            const float v = S[t][r] + rpbh[bidx[t][r]];
            p[t][r] = v;
            mx = fmaxf(mx, v);
        }
    mx = fmaxf(mx, __shfl_xor(mx, 16));
    mx = fmaxf(mx, __shfl_xor(mx, 32));
    float sum = 0.f;
    #pragma unroll
    for (int t = 0; t < 7; ++t)
        #pragma unroll
        for (int r = 0; r < 4; ++r) {
            const float e = __expf(p[t][r] - mx);
            p[t][r] = e;
            sum += e;
        }
    sum += __shfl_xor(sum, 16);
    sum += __shfl_xor(sum, 32);
    const float inv = 1.f / sum;

    // ---- PV: 4 windows of 32 keys; A = P (hi+lo bf16), B = per-lane V gather ----
    f32x4 O0 = {0.f,0.f,0.f,0.f}, O1 = {0.f,0.f,0.f,0.f};
    const u16* vbase = qkv + 512 + w * 32 + q;
    #pragma unroll
    for (int kt = 0; kt < 4; ++kt) {
        const int t0   = 2 * kt;
        const bool has1 = (2 * kt + 1) < 7;
        const int t1   = has1 ? 2 * kt + 1 : 2 * kt;
        bf16x8 ph, pl, vA, vB;
        #pragma unroll
        for (int jj = 0; jj < 4; ++jj) {
            const float a = p[t0][jj] * inv;
            const u16 ha = f2bf(a);
            ph[jj] = (short)ha;
            pl[jj] = (short)f2bf(a - bf2f(ha));
            const float b = has1 ? p[t1][jj] * inv : 0.f;
            const u16 hb = f2bf(b);
            ph[4 + jj] = (short)hb;
            pl[4 + jj] = (short)f2bf(b - bf2f(hb));
            vA[jj]     = (short)vbase[(size_t)vtok[t0][jj] * 768];
            vB[jj]     = (short)vbase[(size_t)vtok[t0][jj] * 768 + 16];
            vA[4 + jj] = (short)vbase[(size_t)vtok[t1][jj] * 768];
            vB[4 + jj] = (short)vbase[(size_t)vtok[t1][jj] * 768 + 16];
        }
        O0 = __builtin_amdgcn_mfma_f32_16x16x32_bf16(ph, vA, O0, 0, 0, 0);
        O0 = __builtin_amdgcn_mfma_f32_16x16x32_bf16(pl, vA, O0, 0, 0, 0);
        O1 = __builtin_amdgcn_mfma_f32_16x16x32_bf16(ph, vB, O1, 0, 0, 0);
        O1 = __builtin_amdgcn_mfma_f32_16x16x32_bf16(pl, vB, O1, 0, 0, 0);
    }

    // ---- park head output in swizzled ao-LDS: rows 4g+r, cols w*32+q / +16 ----
    #pragma unroll
    for (int r = 0; r < 4; ++r) {
        const int row = g * 4 + r;
        const int c0  = w * 4 + (q >> 3);
        const int c1  = c0 + 2;
        ao[row * 256 + ((c0 ^ (row & 7)) << 3) + (q & 7)] = f2bf(O0[r]);
        ao[row * 256 + ((c1 ^ (row & 7)) << 3) + (q & 7)] = f2bf(O1[r]);
    }
    __syncthreads();

    // ---- proj: (16 x 256) @ (256 x 256)^T, 32-col stripe per wave ----
    const int fr  = l & 15;
    const int fc  = l >> 4;
    const int n0w = w * 32;
    f32x4 pacc[2];
    pacc[0] = (f32x4){0.f,0.f,0.f,0.f};
    pacc[1] = (f32x4){0.f,0.f,0.f,0.f};
    #pragma unroll
    for (int ks = 0; ks < 8; ++ks) {
        const int physA = (ks * 4 + fc) ^ (fr & 7);
        const bf16x8 af = *(const bf16x8*)(ao + fr * 256 + physA * 8);
        #pragma unroll
        for (int nt = 0; nt < 2; ++nt) {
            const int n = n0w + nt * 16 + fr;
            const bf16x8 bw = *(const bf16x8*)(projW + (size_t)n * 256 + ks * 32 + fc * 8);
            pacc[nt] = __builtin_amdgcn_mfma_f32_16x16x32_bf16(af, bw, pacc[nt], 0, 0, 0);
        }
    }

    // ---- epilogue: bias + residual -> x1 (f32), block-local LayerNorm2 -> ln2 (bf16) ----
    const int col = l & 15;
    const int rb  = (l >> 4) * 4;
    float vv[2][4];
    float s[4]  = {0.f, 0.f, 0.f, 0.f};
    float sq[4] = {0.f, 0.f, 0.f, 0.f};
    #pragma unroll
    for (int nt = 0; nt < 2; ++nt) {
        const int n = n0w + nt * 16 + col;
        const float bv = proj_b[n];
        #pragma unroll
        for (int r = 0; r < 4; ++r) {
            const int t = rb + r;
            const size_t gi = (size_t)(tokbase + (ti0 + (t >> 2)) * 64 + (tj0 + (t & 3))) * 256 + n;
            float v = pacc[nt][r] + bv + xres[gi];
            x1[gi] = v;
            vv[nt][r] = v;
            s[r]  += v;
            sq[r] += v * v;
        }
    }
    #pragma unroll
    for (int off = 1; off < 16; off <<= 1) {
        #pragma unroll
        for (int r = 0; r < 4; ++r) {
            s[r]  += __shfl_xor(s[r], off);
            sq[r] += __shfl_xor(sq[r], off);
        }
    }
    if (col == 0) {
        #pragma unroll
        for (int r = 0; r < 4; ++r) {
            red[w][rb + r][0] = s[r];
            red[w][rb + r][1] = sq[r];
        }
    }
    __syncthreads();
    float mean[4], rsv[4];
    #pragma unroll
    for (int r = 0; r < 4; ++r) {
        float ts = 0.f, tq = 0.f;
        #pragma unroll
        for (int ww = 0; ww < 8; ++ww) {
            ts += red[ww][rb + r][0];
            tq += red[ww][rb + r][1];
        }
        mean[r] = ts * (1.0f / 256.0f);
        const float var = tq * (1.0f / 256.0f) - mean[r] * mean[r];
        rsv[r]  = rsqrtf(var + 1e-5f);
    }
    #pragma unroll
    for (int nt = 0; nt < 2; ++nt) {
        const int n = n0w + nt * 16 + col;
        const float gv  = g2[n];
        const float bv2 = b2[n];
        #pragma unroll
        for (int r = 0; r < 4; ++r) {
            const int t = rb + r;
            const size_t gi = (size_t)(tokbase + (ti0 + (t >> 2)) * 64 + (tj0 + (t & 3))) * 256 + n;
            ln2[gi] = f2bf((vv[nt][r] - mean[r]) * rsv[r] * gv + bv2);
        }
    }
}

// ---------------- fused MLP: out = x1 + gelu(ln2 @ W1^T + b1) @ W2^T + b2 ----------------
// 256 blocks x 512 thr (8 waves); block = 32-token strip. h (32x1024 bf16) lives in LDS --
// kills the 16 MB hbuf HBM round-trip + one dispatch. W chunks double-buffered (T3-min):
// at 144 KB LDS occupancy is 1 block/CU regardless, so intra-block prefetch is the correct
// regime (R3's occupancy-trade objection doesn't apply). Accumulation order is bitwise
// identical to the split fc1/fc2 kernels (k ascending; h rounded to bf16).
__global__ __launch_bounds__(512) void mlp_kernel(
    const u16* __restrict__ ln2, const u16* __restrict__ W1,
    const float* __restrict__ b1, const u16* __restrict__ W2,
    const float* __restrict__ b2, const float* __restrict__ x1,
    float* __restrict__ out)
{
    __shared__ u16 As[32 * 256];       // ln2 strip, chunk c of row r at phys c^(r&31)
    __shared__ u16 Ws[2][64 * 256];    // W chunk dbuf (phase1: [64][256]; phase2: [256][64])
    __shared__ u16 Hs[32 * 1024];      // h strip, chunk c of row m at phys c^(m&31)

    const int tid = threadIdx.x;
    const int l   = tid & 63;
    const int w   = tid >> 6;
    const int m0  = blockIdx.x * 32;
    const int fr  = l & 15;
    const int fc  = l >> 4;
    const int col = l & 15;
    const int rb  = (l >> 4) * 4;

    // ---- prologue: stage ln2 strip (2 rounds) + W1 chunk 0 (4 rounds) ----
    #pragma unroll
    for (int r = 0; r < 2; ++r) {
        const int s = r * 512 + tid;
        const int row = s >> 5;
        const int c = (s & 31) ^ (row & 31);
        load_lds16(ln2 + (size_t)(m0 + row) * 256 + c * 8, As + s * 8);
    }
    #pragma unroll
    for (int r = 0; r < 4; ++r) {
        const int s = r * 512 + tid;
        const int row = s >> 5;
        const int c = (s & 31) ^ (row & 31);
        load_lds16(W1 + (size_t)row * 256 + c * 8, Ws[0] + s * 8);
    }
    __syncthreads();

    // ---- phase 1: h[32][1024] = gelu(strip @ W1^T + b1), 16 n-chunks of 64 ----
    const int wm1 = (w >> 2) * 16;
    const int wn1 = (w & 3) * 16;
    for (int nc = 0; nc < 16; ++nc) {
        const int nbuf = (nc + 1) & 1;
        if (nc + 1 < 16) {
            #pragma unroll
            for (int r = 0; r < 4; ++r) {
                const int s = r * 512 + tid;
                const int row = s >> 5;
                const int c = (s & 31) ^ (row & 31);
                load_lds16(W1 + (size_t)((nc + 1) * 64 + row) * 256 + c * 8, Ws[nbuf] + s * 8);
            }
        } else {   // prefetch W2 chunk 0 for phase 2 ([256][64] layout)
            #pragma unroll
            for (int r = 0; r < 4; ++r) {
                const int s = r * 512 + tid;
                const int row = s >> 3;
                const int c = (s & 7) ^ (row & 7);
                load_lds16(W2 + (size_t)row * 1024 + c * 8, Ws[nbuf] + s * 8);
            }
        }
        const u16* Wb = Ws[nc & 1];
        f32x4 acc = {0.f, 0.f, 0.f, 0.f};
        #pragma unroll
        for (int ks = 0; ks < 8; ++ks) {
            const int ci = ks * 4 + fc;
            const int ra = wm1 + fr;
            const bf16x8 af = *(const bf16x8*)(As + ra * 256 + ((ci ^ (ra & 31)) << 3));
            const int rw = wn1 + fr;
            const bf16x8 bw = *(const bf16x8*)(Wb + rw * 256 + ((ci ^ (rw & 31)) << 3));
            acc = __builtin_amdgcn_mfma_f32_16x16x32_bf16(af, bw, acc, 0, 0, 0);
        }
        #pragma unroll
        for (int r = 0; r < 4; ++r) {
            const int m = wm1 + rb + r;
            const int ncol = nc * 64 + wn1 + col;
            float v = acc[r] + b1[ncol];
            v = 0.5f * v * (1.0f + erff(v * 0.7071067811865475f));
            const int ci = ncol >> 3;
            Hs[m * 1024 + ((ci ^ (m & 31)) << 3) + (ncol & 7)] = f2bf(v);
        }
        __syncthreads();   // drains prefetch + protects Ws/Hs hazards
    }

    // ---- phase 2: out = h @ W2^T + b2 + x1, 16 k-chunks of 64 ----
    const int wm2 = (w & 1) * 16;
    const int nb  = (w >> 1) * 64;
    f32x4 acc2[4];
    #pragma unroll
    for (int nt = 0; nt < 4; ++nt) acc2[nt] = (f32x4){0.f,0.f,0.f,0.f};

    for (int kc = 0; kc < 16; ++kc) {
        if (kc + 1 < 16) {
            const int nbuf = (kc + 1) & 1;
            #pragma unroll
            for (int r = 0; r < 4; ++r) {
                const int s = r * 512 + tid;
                const int row = s >> 3;
                const int c = (s & 7) ^ (row & 7);
                load_lds16(W2 + (size_t)row * 1024 + (kc + 1) * 64 + c * 8, Ws[nbuf] + s * 8);
            }
        }
        const u16* Wb = Ws[kc & 1];
        #pragma unroll
        for (int ks = 0; ks < 2; ++ks) {
            const int ci = kc * 8 + ks * 4 + fc;
            const int ra = wm2 + fr;
            const bf16x8 af = *(const bf16x8*)(Hs + ra * 1024 + ((ci ^ (ra & 31)) << 3));
            #pragma unroll
            for (int nt = 0; nt < 4; ++nt) {
                const int rr = nb + nt * 16 + fr;
                const bf16x8 bw = *(const bf16x8*)(Wb + rr * 64 + (((ks * 4 + fc) ^ (rr & 7)) << 3));
                acc2[nt] = __builtin_amdgcn_mfma_f32_16x16x32_bf16(af, bw, acc2[nt], 0, 0, 0);
            }
        }
        __syncthreads();
    }

    // ---- epilogue: bias + residual -> out (f32) ----
    #pragma unroll
    for (int nt = 0; nt < 4; ++nt) {
        const int n = nb + nt * 16 + col;
        const float bv = b2[n];
        #pragma unroll
        for (int r = 0; r < 4; ++r) {
            const int m = m0 + wm2 + rb + r;
            const size_t gi = (size_t)m * 256 + n;
            out[gi] = acc2[nt][r] + bv + x1[gi];
        }
    }
}

extern "C" void kernel_launch(void* const* d_in, const int* in_sizes, int n_in,
                              void* d_out, int out_size, void* d_ws, size_t ws_size,
                              hipStream_t stream)
{
    const float* x      = (const float*)d_in[0];
    const float* n1g    = (const float*)d_in[1];
    const float* n1b    = (const float*)d_in[2];
    const float* qkv_w  = (const float*)d_in[3];
    const float* qkv_b  = (const float*)d_in[4];
    const float* rpb    = (const float*)d_in[5];
    const float* proj_w = (const float*)d_in[6];
    const float* proj_b = (const float*)d_in[7];
    const float* n2g    = (const float*)d_in[8];
    const float* n2b    = (const float*)d_in[9];
    const float* fc1_w  = (const float*)d_in[10];
    const float* fc1_b  = (const float*)d_in[11];
    const float* fc2_w  = (const float*)d_in[12];
    const float* fc2_b  = (const float*)d_in[13];
    float* out = (float*)d_out;

    char* wsb = (char*)d_ws;
    u16*   wbf   = (u16*)wsb;                      // 786432 el bf16 weights
    u16*   qkvW  = wbf;
    u16*   projW = wbf + 196608;
    u16*   fc1W  = wbf + 262144;
    u16*   fc2W  = wbf + 524288;
    u16*   ln1   = (u16*)(wsb + 1572864);          // 2M el bf16
    u16*   qkvB  = (u16*)(wsb + 5767168);          // 6M el bf16
    float* x1    = (float*)(wsb + 26738688);       // 2M el f32
    u16*   ln2   = (u16*)(wsb + 35651584);         // 2M el bf16 (must NOT alias qkvB: fused
                                                   // attn kernel reads K/V halos while writing ln2)

    dim3 blk(256);
    prep_kernel<<<2816, blk, 0, stream>>>(qkv_w, proj_w, fc1_w, fc2_w, wbf,
                                          x, n1g, n1b, ln1);
    gemm<128, 64, 768, 256, 1><<<dim3(64, 12), blk, 0, stream>>>(ln1, qkvW, qkv_b, nullptr, qkvB);
    attn_proj_kernel<<<512, dim3(512), 0, stream>>>(qkvB, rpb, projW, proj_b, x, n2g, n2b, x1, ln2);
    mlp_kernel<<<256, dim3(512), 0, stream>>>(ln2, fc1W, fc1_b, fc2W, fc2_b, x1, out);
}

// Round 16
// 143.671 us; speedup vs baseline: 1.0424x; 1.0424x over previous
//
#include <hip/hip_runtime.h>

typedef __attribute__((ext_vector_type(8))) short bf16x8;
typedef __attribute__((ext_vector_type(4))) float f32x4;
typedef unsigned short u16;

__device__ __forceinline__ float bf2f(u16 u) {
    return __builtin_bit_cast(float, ((unsigned int)u) << 16);
}
__device__ __forceinline__ u16 f2bf(float f) {
    unsigned int x = __builtin_bit_cast(unsigned int, f);
    x += 0x7FFFu + ((x >> 16) & 1u);   // RNE
    return (u16)(x >> 16);
}

typedef const __attribute__((address_space(1))) void* gas_t;
typedef __attribute__((address_space(3))) void* las_t;
__device__ __forceinline__ void load_lds16(const u16* g, u16* l) {
    __builtin_amdgcn_global_load_lds((gas_t)g, (las_t)l, 16, 0, 0);
}

// ---------------- prep: weight cvt (blocks 0..767) + LayerNorm1 (blocks 768..2815) ----------------
__global__ __launch_bounds__(256) void prep_kernel(
    const float* __restrict__ s0, const float* __restrict__ s1,
    const float* __restrict__ s2, const float* __restrict__ s3,
    u16* __restrict__ dst,
    const float* __restrict__ x, const float* __restrict__ g,
    const float* __restrict__ b, u16* __restrict__ y)
{
    if (blockIdx.x < 768) {
        const int i4 = (blockIdx.x * 256 + threadIdx.x) * 4;
        const float* src;
        int off;
        if      (i4 < 196608) { src = s0; off = i4; }
        else if (i4 < 262144) { src = s1; off = i4 - 196608; }
        else if (i4 < 524288) { src = s2; off = i4 - 262144; }
        else                  { src = s3; off = i4 - 524288; }
        float4 v = *(const float4*)(src + off);
        ushort4 o;
        o.x = f2bf(v.x); o.y = f2bf(v.y); o.z = f2bf(v.z); o.w = f2bf(v.w);
        *(ushort4*)(dst + i4) = o;
        return;
    }
    const int tok  = (blockIdx.x - 768) * 4 + (threadIdx.x >> 6);
    const int lane = threadIdx.x & 63;
    float4 v = *(const float4*)(x + (size_t)tok * 256 + lane * 4);
    float s  = v.x + v.y + v.z + v.w;
    float sq = v.x*v.x + v.y*v.y + v.z*v.z + v.w*v.w;
    #pragma unroll
    for (int off = 32; off; off >>= 1) {
        s  += __shfl_xor(s, off);
        sq += __shfl_xor(sq, off);
    }
    float mean = s * (1.0f / 256.0f);
    float var  = sq * (1.0f / 256.0f) - mean * mean;
    float rs   = rsqrtf(var + 1e-5f);
    float4 gv = *(const float4*)(g + lane * 4);
    float4 bv = *(const float4*)(b + lane * 4);
    ushort4 o;
    o.x = f2bf((v.x - mean) * rs * gv.x + bv.x);
    o.y = f2bf((v.y - mean) * rs * gv.y + bv.y);
    o.z = f2bf((v.z - mean) * rs * gv.z + bv.z);
    o.w = f2bf((v.w - mean) * rs * gv.w + bv.w);
    *(ushort4*)(y + (size_t)tok * 256 + lane * 4) = o;
}

// ---------------- BMxBN-tile GEMM, BK=64, single-buffer (R2/R9-proven): out = A@W^T + bias ----------------
// EPI: 1 qkv (cols<256 scaled, bf16 out), 2 +f32 residual (f32 out), 3 exact gelu (bf16 out)
template<int BM, int BN, int N, int K, int EPI>
__global__ __launch_bounds__(256) void gemm(
    const u16* __restrict__ A, const u16* __restrict__ W,
    const float* __restrict__ bias, const float* __restrict__ res,
    void* __restrict__ outv)
{
    constexpr int WMT = BM / 32;
    constexpr int WNT = BN / 32;
    constexpr int AR  = BM / 32;
    constexpr int BR  = BN / 32;

    __shared__ u16 As[BM * 64];
    __shared__ u16 Bs[BN * 64];
    const int tid  = threadIdx.x;
    const int lane = tid & 63;
    const int wave = tid >> 6;
    const int m0   = blockIdx.x * BM;
    const int n0   = blockIdx.y * BN;
    const int wm0  = (wave >> 1) * (BM / 2);
    const int wn0  = (wave & 1) * (BN / 2);

    f32x4 acc[WMT][WNT];
    #pragma unroll
    for (int mt = 0; mt < WMT; ++mt)
        #pragma unroll
        for (int nt = 0; nt < WNT; ++nt)
            acc[mt][nt] = (f32x4){0.f, 0.f, 0.f, 0.f};

    int soffA[AR];
    #pragma unroll
    for (int r = 0; r < AR; ++r) {
        const int s   = r * 256 + tid;
        const int row = s >> 3;
        const int c   = (s & 7) ^ (row & 7);
        soffA[r] = row * K + c * 8;
    }
    int soffB[BR];
    #pragma unroll
    for (int r = 0; r < BR; ++r) {
        const int s   = r * 256 + tid;
        const int row = s >> 3;
        const int c   = (s & 7) ^ (row & 7);
        soffB[r] = row * K + c * 8;
    }
    const int fr = lane & 15;
    const int fc = lane >> 4;

    for (int k0 = 0; k0 < K; k0 += 64) {
        __syncthreads();
        #pragma unroll
        for (int r = 0; r < AR; ++r)
            load_lds16(A + (size_t)m0 * K + k0 + soffA[r], As + (r * 256 + tid) * 8);
        #pragma unroll
        for (int r = 0; r < BR; ++r)
            load_lds16(W + (size_t)n0 * K + k0 + soffB[r], Bs + (r * 256 + tid) * 8);
        __syncthreads();
        #pragma unroll
        for (int ks = 0; ks < 2; ++ks) {
            bf16x8 af[WMT], bw[WNT];
            #pragma unroll
            for (int mt = 0; mt < WMT; ++mt) {
                const int rr   = wm0 + mt * 16 + fr;
                const int phys = (ks * 4 + fc) ^ (rr & 7);
                af[mt] = *(const bf16x8*)(As + rr * 64 + phys * 8);
            }
            #pragma unroll
            for (int nt = 0; nt < WNT; ++nt) {
                const int rr   = wn0 + nt * 16 + fr;
                const int phys = (ks * 4 + fc) ^ (rr & 7);
                bw[nt] = *(const bf16x8*)(Bs + rr * 64 + phys * 8);
            }
            #pragma unroll
            for (int mt = 0; mt < WMT; ++mt)
                #pragma unroll
                for (int nt = 0; nt < WNT; ++nt)
                    acc[mt][nt] = __builtin_amdgcn_mfma_f32_16x16x32_bf16(af[mt], bw[nt], acc[mt][nt], 0, 0, 0);
        }
    }

    const int col = lane & 15;
    const int rb  = (lane >> 4) * 4;
    #pragma unroll
    for (int nt = 0; nt < WNT; ++nt) {
        const int n  = n0 + wn0 + nt * 16 + col;
        const float bv = bias[n];
        #pragma unroll
        for (int mt = 0; mt < WMT; ++mt) {
            #pragma unroll
            for (int r = 0; r < 4; ++r) {
                const int m = m0 + wm0 + mt * 16 + rb + r;
                float v = acc[mt][nt][r] + bv;
                if (EPI == 1) {
                    if (n < 256) v *= 0.1767766952966369f;  // 1/sqrt(32), q only
                    ((u16*)outv)[(size_t)m * N + n] = f2bf(v);
                }
                if (EPI == 2) {
                    v += res[(size_t)m * N + n];
                    ((float*)outv)[(size_t)m * N + n] = v;
                }
                if (EPI == 3) {
                    v = 0.5f * v * (1.0f + erff(v * 0.7071067811865475f));
                    ((u16*)outv)[(size_t)m * N + n] = f2bf(v);
                }
            }
        }
    }
}

// ---------- fused MFMA attention (8 waves = 8 heads) + proj + residual + LayerNorm2 ----------
// One 512-thr block per 4x4 tile. K and Q cooperatively staged via coalesced global_load_lds
// (R12-proven; scattered per-lane K/Q gathers were the cost). V stays as the 32B-coalesced
// per-lane gather (LDS re-staging of V measured WORSE, R13). P bf16 hi+lo compensated.
__global__ __launch_bounds__(512) void attn_proj_kernel(
    const u16* __restrict__ qkv, const float* __restrict__ rpb,
    const u16* __restrict__ projW, const float* __restrict__ proj_b,
    const float* __restrict__ xres, const float* __restrict__ g2,
    const float* __restrict__ b2, float* __restrict__ x1,
    u16* __restrict__ ln2)
{
    __shared__ u16   Ks[112 * 256];    // [key][256ch], 16B chunk c at phys c^(key&31)
    __shared__ u16   Qs[16 * 256];     // [tok][256ch], same swizzle
    __shared__ u16   ao[16 * 256];     // attn out, chunk c of row t at c^(t&7)
    __shared__ float rpbs[8 * 177];    // per-head table (169) + sentinel (-1e30)
    __shared__ float red[8][16][2];

    const int tid = threadIdx.x;
    const int l   = tid & 63;
    const int w   = tid >> 6;          // wave = head
    const int B   = blockIdx.x;
    const int tile = (B & 7) * 64 + (B >> 3);   // XCD swizzle over 512 blocks
    const int bb   = tile >> 8;
    const int rem  = tile & 255;
    const int ti0  = (rem >> 4) << 2;
    const int tj0  = (rem & 15) << 2;
    const int oh   = min(max(ti0 - 3, 0), 54);
    const int ow   = min(max(tj0 - 3, 0), 54);
    const int tokbase = bb * 4096;

    // ---- cooperative staging: K (7 rounds), Q (1 round), coalesced + source-swizzled ----
    #pragma unroll
    for (int r = 0; r < 7; ++r) {
        const int s   = r * 512 + tid;
        const int key = s >> 5;                  // 32 chunks per 512B row
        const int pc  = s & 31;
        const int gc  = pc ^ (key & 31);
        const int kkc = min(key, 99);
        const int tr  = (kkc * 205) >> 11, tc = kkc - tr * 10;
        const int tokg = tokbase + (oh + tr) * 64 + (ow + tc);
        load_lds16(qkv + (size_t)tokg * 768 + 256 + gc * 8, Ks + s * 8);
    }
    {
        const int s   = tid;
        const int tok = s >> 5;
        const int pc  = s & 31;
        const int gc  = pc ^ (tok & 31);
        const int tokq = tokbase + (ti0 + (tok >> 2)) * 64 + (tj0 + (tok & 3));
        load_lds16(qkv + (size_t)tokq * 768 + gc * 8, Qs + s * 8);
    }
    #pragma unroll
    for (int r = 0; r < 3; ++r) {
        const int idx = r * 512 + tid;
        if (idx < 1416) {
            const int hh = idx / 177;
            const int ii = idx - hh * 177;
            rpbs[idx] = (ii < 169) ? rpb[hh * 169 + ii] : -1e30f;
        }
    }

    const int q = l & 15;    // doubles as output channel sub-index
    const int g = l >> 4;

    // ---- per-lane bias indices + V tokens (keys 16t+4g+r) ----
    const int i  = ti0 + (q >> 2), j = tj0 + (q & 3);
    const int sh = min(max(i - 3, 0), 57), sw = min(max(j - 3, 0), 57);
    const int khb = sh - oh, kwb = sw - ow;
    const int bh0 = oh - i + 6, bw0 = ow - j + 6;
    int bidx[7][4];
    int vtok[7][4];
    #pragma unroll
    for (int t = 0; t < 7; ++t)
        #pragma unroll
        for (int r = 0; r < 4; ++r) {
            const int kk  = 16 * t + 4 * g + r;
            const int kkc = min(kk, 99);
            const int hr  = (kkc * 205) >> 11;
            const int hc  = kkc - hr * 10;
            vtok[t][r] = tokbase + (oh + hr) * 64 + (ow + hc);
            const bool valid = (kk < 100)
                && ((unsigned)(hr - khb) < 7u) && ((unsigned)(hc - kwb) < 7u);
            bidx[t][r] = valid ? (bh0 + hr) * 13 + (bw0 + hc) : 169;  // sentinel
        }

    __syncthreads();   // staging + rpbs visible to all waves

    // ---- fragment reads from LDS (2-way bank-aliased via chunk-XOR swizzle) ----
    const int cw = w * 4 + g;                    // logical 16B chunk for this head/lane
    const bf16x8 qf = *(const bf16x8*)(Qs + q * 256 + (cw ^ (q & 31)) * 8);
    bf16x8 kf[7];
    #pragma unroll
    for (int t = 0; t < 7; ++t) {
        const int key = 16 * t + q;
        kf[t] = *(const bf16x8*)(Ks + key * 256 + (cw ^ (key & 31)) * 8);
    }

    // ---- QK^T: S[t] reg r = S[key 16t+4g+r][q] ----
    f32x4 S[7];
    #pragma unroll
    for (int t = 0; t < 7; ++t)
        S[t] = __builtin_amdgcn_mfma_f32_16x16x32_bf16(kf[t], qf, (f32x4){0.f,0.f,0.f,0.f}, 0, 0, 0);

    // ---- bias + mask + softmax (in-lane + 2 shfl pairs) ----
    const float* rpbh = rpbs + w * 177;
    float p[7][4];
    float mx = -1e30f;
    #pragma unroll
    for (int t = 0; t < 7; ++t)
        #pragma unroll
        for (int r = 0; r < 4; ++r) {
            const float v = S[t][r] + rpbh[bidx[t][r]];
            p[t][r] = v;
            mx = fmaxf(mx, v);
        }
    mx = fmaxf(mx, __shfl_xor(mx, 16));
    mx = fmaxf(mx, __shfl_xor(mx, 32));
    float sum = 0.f;
    #pragma unroll
    for (int t = 0; t < 7; ++t)
        #pragma unroll
        for (int r = 0; r < 4; ++r) {
            const float e = __expf(p[t][r] - mx);
            p[t][r] = e;
            sum += e;
        }
    sum += __shfl_xor(sum, 16);
    sum += __shfl_xor(sum, 32);
    const float inv = 1.f / sum;

    // ---- PV: 4 windows of 32 keys; A = P (hi+lo bf16), B = per-lane V gather ----
    f32x4 O0 = {0.f,0.f,0.f,0.f}, O1 = {0.f,0.f,0.f,0.f};
    const u16* vbase = qkv + 512 + w * 32 + q;
    #pragma unroll
    for (int kt = 0; kt < 4; ++kt) {
        const int t0   = 2 * kt;
        const bool has1 = (2 * kt + 1) < 7;
        const int t1   = has1 ? 2 * kt + 1 : 2 * kt;
        bf16x8 ph, pl, vA, vB;
        #pragma unroll
        for (int jj = 0; jj < 4; ++jj) {
            const float a = p[t0][jj] * inv;
            const u16 ha = f2bf(a);
            ph[jj] = (short)ha;
            pl[jj] = (short)f2bf(a - bf2f(ha));
            const float b = has1 ? p[t1][jj] * inv : 0.f;
            const u16 hb = f2bf(b);
            ph[4 + jj] = (short)hb;
            pl[4 + jj] = (short)f2bf(b - bf2f(hb));
            vA[jj]     = (short)vbase[(size_t)vtok[t0][jj] * 768];
            vB[jj]     = (short)vbase[(size_t)vtok[t0][jj] * 768 + 16];
            vA[4 + jj] = (short)vbase[(size_t)vtok[t1][jj] * 768];
            vB[4 + jj] = (short)vbase[(size_t)vtok[t1][jj] * 768 + 16];
        }
        O0 = __builtin_amdgcn_mfma_f32_16x16x32_bf16(ph, vA, O0, 0, 0, 0);
        O0 = __builtin_amdgcn_mfma_f32_16x16x32_bf16(pl, vA, O0, 0, 0, 0);
        O1 = __builtin_amdgcn_mfma_f32_16x16x32_bf16(ph, vB, O1, 0, 0, 0);
        O1 = __builtin_amdgcn_mfma_f32_16x16x32_bf16(pl, vB, O1, 0, 0, 0);
    }

    // ---- park head output in swizzled ao-LDS: rows 4g+r, cols w*32+q / +16 ----
    #pragma unroll
    for (int r = 0; r < 4; ++r) {
        const int row = g * 4 + r;
        const int c0  = w * 4 + (q >> 3);
        const int c1  = c0 + 2;
        ao[row * 256 + ((c0 ^ (row & 7)) << 3) + (q & 7)] = f2bf(O0[r]);
        ao[row * 256 + ((c1 ^ (row & 7)) << 3) + (q & 7)] = f2bf(O1[r]);
    }
    __syncthreads();

    // ---- proj: (16 x 256) @ (256 x 256)^T, 32-col stripe per wave ----
    const int fr  = l & 15;
    const int fc  = l >> 4;
    const int n0w = w * 32;
    f32x4 pacc[2];
    pacc[0] = (f32x4){0.f,0.f,0.f,0.f};
    pacc[1] = (f32x4){0.f,0.f,0.f,0.f};
    #pragma unroll
    for (int ks = 0; ks < 8; ++ks) {
        const int physA = (ks * 4 + fc) ^ (fr & 7);
        const bf16x8 af = *(const bf16x8*)(ao + fr * 256 + physA * 8);
        #pragma unroll
        for (int nt = 0; nt < 2; ++nt) {
            const int n = n0w + nt * 16 + fr;
            const bf16x8 bw = *(const bf16x8*)(projW + (size_t)n * 256 + ks * 32 + fc * 8);
            pacc[nt] = __builtin_amdgcn_mfma_f32_16x16x32_bf16(af, bw, pacc[nt], 0, 0, 0);
        }
    }

    // ---- epilogue: bias + residual -> x1 (f32), block-local LayerNorm2 -> ln2 (bf16) ----
    const int col = l & 15;
    const int rb  = (l >> 4) * 4;
    float vv[2][4];
    float s[4]  = {0.f, 0.f, 0.f, 0.f};
    float sq[4] = {0.f, 0.f, 0.f, 0.f};
    #pragma unroll
    for (int nt = 0; nt < 2; ++nt) {
        const int n = n0w + nt * 16 + col;
        const float bv = proj_b[n];
        #pragma unroll
        for (int r = 0; r < 4; ++r) {
            const int t = rb + r;
            const size_t gi = (size_t)(tokbase + (ti0 + (t >> 2)) * 64 + (tj0 + (t & 3))) * 256 + n;
            float v = pacc[nt][r] + bv + xres[gi];
            x1[gi] = v;
            vv[nt][r] = v;
            s[r]  += v;
            sq[r] += v * v;
        }
    }
    #pragma unroll
    for (int off = 1; off < 16; off <<= 1) {
        #pragma unroll
        for (int r = 0; r < 4; ++r) {
            s[r]  += __shfl_xor(s[r], off);
            sq[r] += __shfl_xor(sq[r], off);
        }
    }
    if (col == 0) {
        #pragma unroll
        for (int r = 0; r < 4; ++r) {
            red[w][rb + r][0] = s[r];
            red[w][rb + r][1] = sq[r];
        }
    }
    __syncthreads();
    float mean[4], rsv[4];
    #pragma unroll
    for (int r = 0; r < 4; ++r) {
        float ts = 0.f, tq = 0.f;
        #pragma unroll
        for (int ww = 0; ww < 8; ++ww) {
            ts += red[ww][rb + r][0];
            tq += red[ww][rb + r][1];
        }
        mean[r] = ts * (1.0f / 256.0f);
        const float var = tq * (1.0f / 256.0f) - mean[r] * mean[r];
        rsv[r]  = rsqrtf(var + 1e-5f);
    }
    #pragma unroll
    for (int nt = 0; nt < 2; ++nt) {
        const int n = n0w + nt * 16 + col;
        const float gv  = g2[n];
        const float bv2 = b2[n];
        #pragma unroll
        for (int r = 0; r < 4; ++r) {
            const int t = rb + r;
            const size_t gi = (size_t)(tokbase + (ti0 + (t >> 2)) * 64 + (tj0 + (t & 3))) * 256 + n;
            ln2[gi] = f2bf((vv[nt][r] - mean[r]) * rsv[r] * gv + bv2);
        }
    }
}

extern "C" void kernel_launch(void* const* d_in, const int* in_sizes, int n_in,
                              void* d_out, int out_size, void* d_ws, size_t ws_size,
                              hipStream_t stream)
{
    const float* x      = (const float*)d_in[0];
    const float* n1g    = (const float*)d_in[1];
    const float* n1b    = (const float*)d_in[2];
    const float* qkv_w  = (const float*)d_in[3];
    const float* qkv_b  = (const float*)d_in[4];
    const float* rpb    = (const float*)d_in[5];
    const float* proj_w = (const float*)d_in[6];
    const float* proj_b = (const float*)d_in[7];
    const float* n2g    = (const float*)d_in[8];
    const float* n2b    = (const float*)d_in[9];
    const float* fc1_w  = (const float*)d_in[10];
    const float* fc1_b  = (const float*)d_in[11];
    const float* fc2_w  = (const float*)d_in[12];
    const float* fc2_b  = (const float*)d_in[13];
    float* out = (float*)d_out;

    char* wsb = (char*)d_ws;
    u16*   wbf   = (u16*)wsb;                      // 786432 el bf16 weights
    u16*   qkvW  = wbf;
    u16*   projW = wbf + 196608;
    u16*   fc1W  = wbf + 262144;
    u16*   fc2W  = wbf + 524288;
    u16*   ln1   = (u16*)(wsb + 1572864);          // 2M el bf16
    u16*   qkvB  = (u16*)(wsb + 5767168);          // 6M el bf16
    u16*   hbuf  = (u16*)(wsb + 9961472);          // 8M el bf16
    float* x1    = (float*)(wsb + 26738688);       // 2M el f32
    u16*   ln2   = (u16*)(wsb + 35651584);         // 2M el bf16 (must NOT alias qkvB: fused
                                                   // kernel reads K/V halos while writing ln2)

    dim3 blk(256);
    prep_kernel<<<2816, blk, 0, stream>>>(qkv_w, proj_w, fc1_w, fc2_w, wbf,
                                          x, n1g, n1b, ln1);
    gemm<128, 64, 768, 256, 1><<<dim3(64, 12), blk, 0, stream>>>(ln1, qkvW, qkv_b, nullptr, qkvB);
    attn_proj_kernel<<<512, dim3(512), 0, stream>>>(qkvB, rpb, projW, proj_b, x, n2g, n2b, x1, ln2);
    gemm<128, 64, 1024, 256, 3><<<dim3(64, 16), blk, 0, stream>>>(ln2, fc1W, fc1_b, nullptr, hbuf);
    gemm<64, 64, 256, 1024, 2><<<dim3(128, 4), blk, 0, stream>>>(hbuf, fc2W, fc2_b, x1, out);
}